// Round 5
// baseline (428.603 us; speedup 1.0000x reference)
//
#include <hip/hip_runtime.h>

namespace {

constexpr int H = 1024;
constexpr int W = 1024;
constexpr int PLANE = H * W;
constexpr int CIN = 18;     // total input channels
constexpr int C = 8;        // filterable channels
constexpr int TX = 16;
constexpr int TY = 16;      // threads in y; each thread does 2 vertical pixels
constexpr int TILE_H = 32;  // output rows per block
constexpr int SW = TX + 6;      // 22 halo width
constexpr int SH = TILE_H + 6;  // 38 halo height
constexpr int NPOS = SW * SH;   // 836 positions
constexpr float LOG2E = 1.44269504088896340736f;

typedef _Float16 half2_t __attribute__((ext_vector_type(2)));
typedef _Float16 half8_t __attribute__((ext_vector_type(8)));

__device__ __forceinline__ float dot2acc(half2_t a, half2_t b, float c) {
#if defined(__has_builtin)
#if __has_builtin(__builtin_amdgcn_fdot2)
    return __builtin_amdgcn_fdot2(a, b, c, false);
#else
    return fmaf((float)a[0], (float)b[0], fmaf((float)a[1], (float)b[1], c));
#endif
#else
    return fmaf((float)a[0], (float)b[0], fmaf((float)a[1], (float)b[1], c));
#endif
}

__device__ __forceinline__ float fast_exp2(float x) {
#if defined(__has_builtin)
#if __has_builtin(__builtin_amdgcn_exp2f)
    return __builtin_amdgcn_exp2f(x);
#else
    return exp2f(x);
#endif
#else
    return exp2f(x);
#endif
}

template<bool INTERIOR>
__device__ __forceinline__ void run_tile(const float* __restrict__ inb,
                                         float* __restrict__ outb,
                                         half8_t* __restrict__ tile,
                                         float* __restrict__ msk,
                                         int gy0, int gx0)
{
    const int tx = threadIdx.x, ty = threadIdx.y;
    const int tid = ty * TX + tx;

    const int o0 = gy0 + 2 * ty;      // first output row of this thread
    const int gx = gx0 + tx;
    const int pofs0 = o0 * W + gx;    // pixel 0; pixel 1 = pofs0 + W

    // ---- per-pixel params for BOTH pixels first (their global latency
    // overlaps the staging loop + barrier). Packed pairwise to keep live
    // ranges short (R4 spilled partly from held f32 arrays).
    half2_t rp01_0, rp23_0, rp45_0, rp67_0;
    half2_t rp01_1, rp23_1, rp45_1, rp67_1;
    float sxf0, syf0, sxf1, syf1;
    {
        const float* pp = inb + (size_t)C * PLANE + pofs0;
#define PAIR(DST0, DST1, CA, CB) do {                                     \
        float a0_ = pp[(size_t)(CA) * PLANE];                             \
        float b0_ = pp[(size_t)(CB) * PLANE];                             \
        float a1_ = pp[(size_t)(CA) * PLANE + W];                         \
        float b1_ = pp[(size_t)(CB) * PLANE + W];                         \
        DST0 = half2_t{(_Float16)(-(a0_ * a0_) * LOG2E),                  \
                       (_Float16)(-(b0_ * b0_) * LOG2E)};                 \
        DST1 = half2_t{(_Float16)(-(a1_ * a1_) * LOG2E),                  \
                       (_Float16)(-(b1_ * b1_) * LOG2E)};                 \
    } while (0)
        PAIR(rp01_0, rp01_1, 0, 1);
        PAIR(rp23_0, rp23_1, 2, 3);
        PAIR(rp45_0, rp45_1, 4, 5);
        PAIR(rp67_0, rp67_1, 6, 7);
#undef PAIR
        float px0 = pp[(size_t)8 * PLANE];
        float py0 = pp[(size_t)9 * PLANE];
        float px1 = pp[(size_t)8 * PLANE + W];
        float py1 = pp[(size_t)9 * PLANE + W];
        sxf0 = -(px0 * px0) * LOG2E;  syf0 = -(py0 * py0) * LOG2E;
        sxf1 = -(px1 * px1) * LOG2E;  syf1 = -(py1 * py1) * LOG2E;
    }

    // ---- stage: unroll 2 (R4's x4 unroll held ~64 VGPRs of in-flight
    // loads -> 197MB scratch spill at the 128 cap; x2 overlaps latency once
    // at half the pressure)
#pragma unroll 2
    for (int it = 0; it < 4; ++it) {
        int idx = tid + it * (TX * TY);
        if (idx < NPOS) {
            int y = idx / SW;
            int x = idx - y * SW;
            int sy_ = gy0 + y - 3;
            int sx_ = gx0 + x - 3;
            half8_t hv;
            if (INTERIOR || ((unsigned)sy_ < (unsigned)H && (unsigned)sx_ < (unsigned)W)) {
                const float* p = inb + sy_ * W + sx_;
#pragma unroll
                for (int c = 0; c < C; ++c) hv[c] = (_Float16)p[(size_t)c * PLANE];
                if (!INTERIOR) msk[idx] = 1.0f;
            } else {
#pragma unroll
                for (int c = 0; c < C; ++c) hv[c] = (_Float16)0.0f;
                msk[idx] = 0.0f;
            }
            tile[idx] = hv;
        }
    }
    __syncthreads();

    // halo-row origin for this thread: window of px0 starts at halo row 2*ty
    const half8_t* lp = tile + (2 * ty) * SW + tx;
    const half8_t fc0 = lp[3 * SW + 3];  // center of px0
    const half8_t fc1 = lp[4 * SW + 3];  // center of px1

    float a00 = 0.f, a01 = 0.f, a02 = 0.f, ws0 = 0.f;
    float a10 = 0.f, a11 = 0.f, a12 = 0.f, ws1 = 0.f;

    half8_t q0_, q1_, q2_, q3_, q4_, q5_, q6_;

#define LOADROW(I) do { const half8_t* lq_ = lp + (I) * SW;              \
        q0_ = lq_[0]; q1_ = lq_[1]; q2_ = lq_[2]; q3_ = lq_[3];          \
        q4_ = lq_[4]; q5_ = lq_[5]; q6_ = lq_[6]; } while (0)

#define PIXA(Q, J) do {                                                  \
        half8_t d_ = (Q) - fc0;                                          \
        half8_t dd_ = d_ * d_;                                           \
        float lw_ = fmaf((float)(((J) - 3) * ((J) - 3)), sxf0, rs0_);    \
        lw_ = dot2acc(__builtin_shufflevector(dd_, dd_, 0, 1), rp01_0, lw_); \
        lw_ = dot2acc(__builtin_shufflevector(dd_, dd_, 2, 3), rp23_0, lw_); \
        lw_ = dot2acc(__builtin_shufflevector(dd_, dd_, 4, 5), rp45_0, lw_); \
        lw_ = dot2acc(__builtin_shufflevector(dd_, dd_, 6, 7), rp67_0, lw_); \
        float w_ = fast_exp2(lw_);                                       \
        if (!INTERIOR) w_ *= mrow_[(J)];                                 \
        ws0 += w_;                                                       \
        a00 = fmaf(w_, (float)(Q)[0], a00);                              \
        a01 = fmaf(w_, (float)(Q)[1], a01);                              \
        a02 = fmaf(w_, (float)(Q)[2], a02);                              \
    } while (0)

#define PIXB(Q, J) do {                                                  \
        half8_t d_ = (Q) - fc1;                                          \
        half8_t dd_ = d_ * d_;                                           \
        float lw_ = fmaf((float)(((J) - 3) * ((J) - 3)), sxf1, rs1_);    \
        lw_ = dot2acc(__builtin_shufflevector(dd_, dd_, 0, 1), rp01_1, lw_); \
        lw_ = dot2acc(__builtin_shufflevector(dd_, dd_, 2, 3), rp23_1, lw_); \
        lw_ = dot2acc(__builtin_shufflevector(dd_, dd_, 4, 5), rp45_1, lw_); \
        lw_ = dot2acc(__builtin_shufflevector(dd_, dd_, 6, 7), rp67_1, lw_); \
        float w_ = fast_exp2(lw_);                                       \
        if (!INTERIOR) w_ *= mrow_[(J)];                                 \
        ws1 += w_;                                                       \
        a10 = fmaf(w_, (float)(Q)[0], a10);                              \
        a11 = fmaf(w_, (float)(Q)[1], a11);                              \
        a12 = fmaf(w_, (float)(Q)[2], a12);                              \
    } while (0)

#define ROW_COMMON(I)                                                    \
        LOADROW(I);                                                      \
        const float* mrow_ = msk + (2 * ty + (I)) * SW + tx;             \
        (void)mrow_;

#define ROW_FIRST(I) {                                                   \
        ROW_COMMON(I)                                                    \
        const float rs0_ = syf0 * (float)(((I) - 3) * ((I) - 3));        \
        PIXA(q0_, 0); PIXA(q1_, 1); PIXA(q2_, 2); PIXA(q3_, 3);          \
        PIXA(q4_, 4); PIXA(q5_, 5); PIXA(q6_, 6);                        \
    }

#define ROW_BOTH(I) {                                                    \
        ROW_COMMON(I)                                                    \
        const float rs0_ = syf0 * (float)(((I) - 3) * ((I) - 3));        \
        const float rs1_ = syf1 * (float)(((I) - 4) * ((I) - 4));        \
        PIXA(q0_, 0); PIXB(q0_, 0); PIXA(q1_, 1); PIXB(q1_, 1);          \
        PIXA(q2_, 2); PIXB(q2_, 2); PIXA(q3_, 3); PIXB(q3_, 3);          \
        PIXA(q4_, 4); PIXB(q4_, 4); PIXA(q5_, 5); PIXB(q5_, 5);          \
        PIXA(q6_, 6); PIXB(q6_, 6);                                      \
    }

#define ROW_LAST(I) {                                                    \
        ROW_COMMON(I)                                                    \
        const float rs1_ = syf1 * (float)(((I) - 4) * ((I) - 4));        \
        PIXB(q0_, 0); PIXB(q1_, 1); PIXB(q2_, 2); PIXB(q3_, 3);          \
        PIXB(q4_, 4); PIXB(q5_, 5); PIXB(q6_, 6);                        \
    }

    ROW_FIRST(0)
    ROW_BOTH(1)
    ROW_BOTH(2)
    ROW_BOTH(3)
    ROW_BOTH(4)
    ROW_BOTH(5)
    ROW_BOTH(6)
    ROW_LAST(7)

#undef ROW_LAST
#undef ROW_BOTH
#undef ROW_FIRST
#undef ROW_COMMON
#undef PIXB
#undef PIXA
#undef LOADROW

    const float inv0 = 1.0f / ws0;
    const float inv1 = 1.0f / ws1;
    outb[pofs0]                 = a00 * inv0;
    outb[PLANE + pofs0]         = a01 * inv0;
    outb[2 * PLANE + pofs0]     = a02 * inv0;
    outb[pofs0 + W]             = a10 * inv1;
    outb[PLANE + pofs0 + W]     = a11 * inv1;
    outb[2 * PLANE + pofs0 + W] = a12 * inv1;
}

// VGPR-cap model (empirical, this toolchain): launch_bounds(256,N) caps
// VGPRs at 256/N: (256,8)->32, (256,4)->64, (256,2)->128 (R4 confirmed).
// R4 spilled 197MB AT the 128 cap -> pressure came from the x4-unrolled
// staging loop (~64 in-flight regs), not the window loop (~80). This rev:
// staging unroll x2, pairwise param packing, same (256,2).
__global__ __launch_bounds__(TX * TY, 2) void bilateral_kernel(const float* __restrict__ in,
                                                               float* __restrict__ out)
{
    __shared__ __align__(16) half8_t tile[NPOS];
    __shared__ float msk[NPOS];
    const int b = blockIdx.z;
    const int gx0 = blockIdx.x * TX;
    const int gy0 = blockIdx.y * TILE_H;
    const float* inb = in + (size_t)b * CIN * PLANE;
    float* outb = out + (size_t)b * 3 * PLANE;

    const bool interior = (gx0 >= 3) && (gx0 + TX + 3 <= W) &&
                          (gy0 >= 3) && (gy0 + TILE_H + 3 <= H);
    if (interior)
        run_tile<true>(inb, outb, tile, msk, gy0, gx0);
    else
        run_tile<false>(inb, outb, tile, msk, gy0, gx0);
}

} // namespace

extern "C" void kernel_launch(void* const* d_in, const int* in_sizes, int n_in,
                              void* d_out, int out_size, void* d_ws, size_t ws_size,
                              hipStream_t stream)
{
    const float* in = (const float*)d_in[0];
    float* out = (float*)d_out;
    dim3 grid(W / TX, H / TILE_H, 2);
    dim3 block(TX, TY);
    hipLaunchKernelGGL(bilateral_kernel, grid, block, 0, stream, in, out);
}

// Round 6
// 258.405 us; speedup vs baseline: 1.6587x; 1.6587x over previous
//
#include <hip/hip_runtime.h>

namespace {

constexpr int H = 1024;
constexpr int W = 1024;
constexpr int PLANE = H * W;
constexpr int CIN = 18;     // total input channels
constexpr int C = 8;        // filterable channels
constexpr int TX = 16;
constexpr int TY = 16;      // threads in y; each thread does 2 vertical pixels
constexpr int TILE_H = 32;  // output rows per block
constexpr int SW = TX + 6;      // 22 halo width
constexpr int SH = TILE_H + 6;  // 38 halo height
constexpr int NPOS = SW * SH;   // 836 positions
constexpr float LOG2E = 1.44269504088896340736f;

typedef _Float16 half2_t __attribute__((ext_vector_type(2)));
typedef _Float16 half8_t __attribute__((ext_vector_type(8)));

__device__ __forceinline__ float dot2acc(half2_t a, half2_t b, float c) {
#if defined(__has_builtin)
#if __has_builtin(__builtin_amdgcn_fdot2)
    return __builtin_amdgcn_fdot2(a, b, c, false);
#else
    return fmaf((float)a[0], (float)b[0], fmaf((float)a[1], (float)b[1], c));
#endif
#else
    return fmaf((float)a[0], (float)b[0], fmaf((float)a[1], (float)b[1], c));
#endif
}

__device__ __forceinline__ float fast_exp2(float x) {
#if defined(__has_builtin)
#if __has_builtin(__builtin_amdgcn_exp2f)
    return __builtin_amdgcn_exp2f(x);
#else
    return exp2f(x);
#endif
#else
    return exp2f(x);
#endif
}

template<bool INTERIOR>
__device__ __forceinline__ void run_tile(const float* __restrict__ inb,
                                         float* __restrict__ outb,
                                         half8_t* __restrict__ tile,
                                         float* __restrict__ msk,
                                         int gy0, int gx0)
{
    const int tx = threadIdx.x, ty = threadIdx.y;
    const int tid = ty * TX + tx;

    const int o0 = gy0 + 2 * ty;      // first output row of this thread
    const int gx = gx0 + tx;
    const int pofs0 = o0 * W + gx;    // pixel 0; pixel 1 = pofs0 + W

    // ---- per-pixel params for BOTH pixels first (their global latency
    // overlaps the staging loop + barrier). Packed pairwise.
    half2_t rp01_0, rp23_0, rp45_0, rp67_0;
    half2_t rp01_1, rp23_1, rp45_1, rp67_1;
    float sxf0, syf0, sxf1, syf1;
    {
        const float* pp = inb + (size_t)C * PLANE + pofs0;
#define PAIR(DST0, DST1, CA, CB) do {                                     \
        float a0_ = pp[(size_t)(CA) * PLANE];                             \
        float b0_ = pp[(size_t)(CB) * PLANE];                             \
        float a1_ = pp[(size_t)(CA) * PLANE + W];                         \
        float b1_ = pp[(size_t)(CB) * PLANE + W];                         \
        DST0 = half2_t{(_Float16)(-(a0_ * a0_) * LOG2E),                  \
                       (_Float16)(-(b0_ * b0_) * LOG2E)};                 \
        DST1 = half2_t{(_Float16)(-(a1_ * a1_) * LOG2E),                  \
                       (_Float16)(-(b1_ * b1_) * LOG2E)};                 \
    } while (0)
        PAIR(rp01_0, rp01_1, 0, 1);
        PAIR(rp23_0, rp23_1, 2, 3);
        PAIR(rp45_0, rp45_1, 4, 5);
        PAIR(rp67_0, rp67_1, 6, 7);
#undef PAIR
        float px0 = pp[(size_t)8 * PLANE];
        float py0 = pp[(size_t)9 * PLANE];
        float px1 = pp[(size_t)8 * PLANE + W];
        float py1 = pp[(size_t)9 * PLANE + W];
        sxf0 = -(px0 * px0) * LOG2E;  syf0 = -(py0 * py0) * LOG2E;
        sxf1 = -(px1 * px1) * LOG2E;  syf1 = -(py1 * py1) * LOG2E;
    }

    // ---- stage: simple strided loop, NOT unrolled (R2 ran this shape at
    // 48 VGPR spill-free; unrolled variants only added pressure)
#pragma unroll 1
    for (int idx = tid; idx < NPOS; idx += TX * TY) {
        int y = idx / SW;
        int x = idx - y * SW;
        int sy_ = gy0 + y - 3;
        int sx_ = gx0 + x - 3;
        half8_t hv;
        if (INTERIOR || ((unsigned)sy_ < (unsigned)H && (unsigned)sx_ < (unsigned)W)) {
            const float* p = inb + sy_ * W + sx_;
#pragma unroll
            for (int c = 0; c < C; ++c) hv[c] = (_Float16)p[(size_t)c * PLANE];
            if (!INTERIOR) msk[idx] = 1.0f;
        } else {
#pragma unroll
            for (int c = 0; c < C; ++c) hv[c] = (_Float16)0.0f;
            msk[idx] = 0.0f;
        }
        tile[idx] = hv;
    }
    __syncthreads();

    // halo-row origin for this thread: window of px0 starts at halo row 2*ty
    const half8_t* lp = tile + (2 * ty) * SW + tx;
    const half8_t fc0 = lp[3 * SW + 3];  // center of px0
    const half8_t fc1 = lp[4 * SW + 3];  // center of px1

    float a00 = 0.f, a01 = 0.f, a02 = 0.f, ws0 = 0.f;
    float a10 = 0.f, a11 = 0.f, a12 = 0.f, ws1 = 0.f;

#define PIX(Q, RP01, RP23, RP45, RP67, SXF, RS, MUL, WS, A0, A1, A2, J) do { \
        half8_t d_ = (Q) - (MUL);                                        \
        half8_t dd_ = d_ * d_;                                           \
        float lw_ = fmaf((float)(((J) - 3) * ((J) - 3)), (SXF), (RS));   \
        lw_ = dot2acc(__builtin_shufflevector(dd_, dd_, 0, 1), RP01, lw_); \
        lw_ = dot2acc(__builtin_shufflevector(dd_, dd_, 2, 3), RP23, lw_); \
        lw_ = dot2acc(__builtin_shufflevector(dd_, dd_, 4, 5), RP45, lw_); \
        lw_ = dot2acc(__builtin_shufflevector(dd_, dd_, 6, 7), RP67, lw_); \
        float w_ = fast_exp2(lw_);                                       \
        if (!INTERIOR) w_ *= mrow_[(J)];                                 \
        WS += w_;                                                        \
        A0 = fmaf(w_, (float)(Q)[0], A0);                                \
        A1 = fmaf(w_, (float)(Q)[1], A1);                                \
        A2 = fmaf(w_, (float)(Q)[2], A2);                                \
    } while (0)

    // ---- row loop kept as a REAL loop: bounds the scheduler's region so
    // it cannot hoist many rows of ds_reads (R3/R4/R5: full unroll ->
    // ~175-reg demanded schedule -> 0.2-1.2GB scratch spill). Row validity
    // per pixel is a wave-uniform branch on the loop counter (free).
#pragma unroll 1
    for (int i = 0; i < 8; ++i) {
        const half8_t* lq_ = lp + i * SW;
        half8_t q0_ = lq_[0], q1_ = lq_[1], q2_ = lq_[2], q3_ = lq_[3],
                q4_ = lq_[4], q5_ = lq_[5], q6_ = lq_[6];
        const float* mrow_ = msk + (2 * ty + i) * SW + tx;
        (void)mrow_;
        if (i != 7) {  // contributes to pixel 0 (window rows 0..6)
            const float rs0_ = syf0 * (float)((i - 3) * (i - 3));
            PIX(q0_, rp01_0, rp23_0, rp45_0, rp67_0, sxf0, rs0_, fc0, ws0, a00, a01, a02, 0);
            PIX(q1_, rp01_0, rp23_0, rp45_0, rp67_0, sxf0, rs0_, fc0, ws0, a00, a01, a02, 1);
            PIX(q2_, rp01_0, rp23_0, rp45_0, rp67_0, sxf0, rs0_, fc0, ws0, a00, a01, a02, 2);
            PIX(q3_, rp01_0, rp23_0, rp45_0, rp67_0, sxf0, rs0_, fc0, ws0, a00, a01, a02, 3);
            PIX(q4_, rp01_0, rp23_0, rp45_0, rp67_0, sxf0, rs0_, fc0, ws0, a00, a01, a02, 4);
            PIX(q5_, rp01_0, rp23_0, rp45_0, rp67_0, sxf0, rs0_, fc0, ws0, a00, a01, a02, 5);
            PIX(q6_, rp01_0, rp23_0, rp45_0, rp67_0, sxf0, rs0_, fc0, ws0, a00, a01, a02, 6);
        }
        if (i != 0) {  // contributes to pixel 1 (its window rows 0..6 = halo 1..7)
            const float rs1_ = syf1 * (float)((i - 4) * (i - 4));
            PIX(q0_, rp01_1, rp23_1, rp45_1, rp67_1, sxf1, rs1_, fc1, ws1, a10, a11, a12, 0);
            PIX(q1_, rp01_1, rp23_1, rp45_1, rp67_1, sxf1, rs1_, fc1, ws1, a10, a11, a12, 1);
            PIX(q2_, rp01_1, rp23_1, rp45_1, rp67_1, sxf1, rs1_, fc1, ws1, a10, a11, a12, 2);
            PIX(q3_, rp01_1, rp23_1, rp45_1, rp67_1, sxf1, rs1_, fc1, ws1, a10, a11, a12, 3);
            PIX(q4_, rp01_1, rp23_1, rp45_1, rp67_1, sxf1, rs1_, fc1, ws1, a10, a11, a12, 4);
            PIX(q5_, rp01_1, rp23_1, rp45_1, rp67_1, sxf1, rs1_, fc1, ws1, a10, a11, a12, 5);
            PIX(q6_, rp01_1, rp23_1, rp45_1, rp67_1, sxf1, rs1_, fc1, ws1, a10, a11, a12, 6);
        }
    }
#undef PIX

    const float inv0 = 1.0f / ws0;
    const float inv1 = 1.0f / ws1;
    outb[pofs0]                 = a00 * inv0;
    outb[PLANE + pofs0]         = a01 * inv0;
    outb[2 * PLANE + pofs0]     = a02 * inv0;
    outb[pofs0 + W]             = a10 * inv1;
    outb[PLANE + pofs0 + W]     = a11 * inv1;
    outb[2 * PLANE + pofs0 + W] = a12 * inv1;
}

// VGPR-cap model (empirical): launch_bounds(256,N) caps at 256/N:
// (256,8)->32, (256,4)->64, (256,2)->128 (R4/R5). Full 8-row unroll lets
// the pre-RA scheduler hoist ds_reads across rows -> demanded ~175 regs ->
// spill at ANY cap (R3: 1.2GB@64, R4/R5: 0.22GB@128). Looped rows bound
// the scheduling region instead.
__global__ __launch_bounds__(TX * TY, 2) void bilateral_kernel(const float* __restrict__ in,
                                                               float* __restrict__ out)
{
    __shared__ __align__(16) half8_t tile[NPOS];
    __shared__ float msk[NPOS];
    const int b = blockIdx.z;
    const int gx0 = blockIdx.x * TX;
    const int gy0 = blockIdx.y * TILE_H;
    const float* inb = in + (size_t)b * CIN * PLANE;
    float* outb = out + (size_t)b * 3 * PLANE;

    const bool interior = (gx0 >= 3) && (gx0 + TX + 3 <= W) &&
                          (gy0 >= 3) && (gy0 + TILE_H + 3 <= H);
    if (interior)
        run_tile<true>(inb, outb, tile, msk, gy0, gx0);
    else
        run_tile<false>(inb, outb, tile, msk, gy0, gx0);
}

} // namespace

extern "C" void kernel_launch(void* const* d_in, const int* in_sizes, int n_in,
                              void* d_out, int out_size, void* d_ws, size_t ws_size,
                              hipStream_t stream)
{
    const float* in = (const float*)d_in[0];
    float* out = (float*)d_out;
    dim3 grid(W / TX, H / TILE_H, 2);
    dim3 block(TX, TY);
    hipLaunchKernelGGL(bilateral_kernel, grid, block, 0, stream, in, out);
}

// Round 7
// 255.507 us; speedup vs baseline: 1.6775x; 1.0113x over previous
//
#include <hip/hip_runtime.h>

namespace {

constexpr int H = 1024;
constexpr int W = 1024;
constexpr int PLANE = H * W;
constexpr int CIN = 18;     // total input channels
constexpr int C = 8;        // filterable channels
constexpr int TX = 16;
constexpr int TY = 16;      // threads in y; each thread does 2 vertical pixels
constexpr int TILE_H = 32;  // output rows per block
constexpr int SW = TX + 6;      // 22 halo width
constexpr int SH = TILE_H + 6;  // 38 halo height
constexpr int NPOS = SW * SH;   // 836 positions
constexpr float LOG2E = 1.44269504088896340736f;

typedef _Float16 half2_t __attribute__((ext_vector_type(2)));
typedef _Float16 half8_t __attribute__((ext_vector_type(8)));

__device__ __forceinline__ float dot2acc(half2_t a, half2_t b, float c) {
#if defined(__has_builtin)
#if __has_builtin(__builtin_amdgcn_fdot2)
    return __builtin_amdgcn_fdot2(a, b, c, false);
#else
    return fmaf((float)a[0], (float)b[0], fmaf((float)a[1], (float)b[1], c));
#endif
#else
    return fmaf((float)a[0], (float)b[0], fmaf((float)a[1], (float)b[1], c));
#endif
}

__device__ __forceinline__ float fast_exp2(float x) {
#if defined(__has_builtin)
#if __has_builtin(__builtin_amdgcn_exp2f)
    return __builtin_amdgcn_exp2f(x);
#else
    return exp2f(x);
#endif
#else
    return exp2f(x);
#endif
}

template<bool INTERIOR>
__device__ __forceinline__ void run_tile(const float* __restrict__ inb,
                                         float* __restrict__ outb,
                                         half8_t* __restrict__ tile,
                                         float* __restrict__ msk,
                                         int gy0, int gx0)
{
    const int tx = threadIdx.x, ty = threadIdx.y;
    const int tid = ty * TX + tx;

    const int o0 = gy0 + 2 * ty;      // first output row of this thread
    const int gx = gx0 + tx;
    const int pofs0 = o0 * W + gx;    // pixel 0; pixel 1 = pofs0 + W

    // ---- per-pixel params for BOTH pixels first (their global latency
    // overlaps the staging loop + barrier). Packed pairwise.
    half2_t rp01_0, rp23_0, rp45_0, rp67_0;
    half2_t rp01_1, rp23_1, rp45_1, rp67_1;
    float sxf0, syf0, sxf1, syf1;
    {
        const float* pp = inb + (size_t)C * PLANE + pofs0;
#define PAIR(DST0, DST1, CA, CB) do {                                     \
        float a0_ = pp[(size_t)(CA) * PLANE];                             \
        float b0_ = pp[(size_t)(CB) * PLANE];                             \
        float a1_ = pp[(size_t)(CA) * PLANE + W];                         \
        float b1_ = pp[(size_t)(CB) * PLANE + W];                         \
        DST0 = half2_t{(_Float16)(-(a0_ * a0_) * LOG2E),                  \
                       (_Float16)(-(b0_ * b0_) * LOG2E)};                 \
        DST1 = half2_t{(_Float16)(-(a1_ * a1_) * LOG2E),                  \
                       (_Float16)(-(b1_ * b1_) * LOG2E)};                 \
    } while (0)
        PAIR(rp01_0, rp01_1, 0, 1);
        PAIR(rp23_0, rp23_1, 2, 3);
        PAIR(rp45_0, rp45_1, 4, 5);
        PAIR(rp67_0, rp67_1, 6, 7);
#undef PAIR
        float px0 = pp[(size_t)8 * PLANE];
        float py0 = pp[(size_t)9 * PLANE];
        float px1 = pp[(size_t)8 * PLANE + W];
        float py1 = pp[(size_t)9 * PLANE + W];
        sxf0 = -(px0 * px0) * LOG2E;  syf0 = -(py0 * py0) * LOG2E;
        sxf1 = -(px1 * px1) * LOG2E;  syf1 = -(py1 * py1) * LOG2E;
    }

    // ---- stage: unroll 2 -> two rounds of 16 in-flight global loads
    // instead of 4 serialized ~900cy rounds (R6 unroll-1 exposed all 4).
#pragma unroll 2
    for (int idx = tid; idx < NPOS; idx += TX * TY) {
        int y = idx / SW;
        int x = idx - y * SW;
        int sy_ = gy0 + y - 3;
        int sx_ = gx0 + x - 3;
        half8_t hv;
        if (INTERIOR || ((unsigned)sy_ < (unsigned)H && (unsigned)sx_ < (unsigned)W)) {
            const float* p = inb + sy_ * W + sx_;
#pragma unroll
            for (int c = 0; c < C; ++c) hv[c] = (_Float16)p[(size_t)c * PLANE];
            if (!INTERIOR) msk[idx] = 1.0f;
        } else {
#pragma unroll
            for (int c = 0; c < C; ++c) hv[c] = (_Float16)0.0f;
            msk[idx] = 0.0f;
        }
        tile[idx] = hv;
    }
    __syncthreads();

    // halo-row origin for this thread: window of px0 starts at halo row 2*ty
    const half8_t* lp = tile + (2 * ty) * SW + tx;
    const half8_t fc0 = lp[3 * SW + 3];  // center of px0
    const half8_t fc1 = lp[4 * SW + 3];  // center of px1

    float a00 = 0.f, a01 = 0.f, a02 = 0.f, ws0 = 0.f;
    float a10 = 0.f, a11 = 0.f, a12 = 0.f, ws1 = 0.f;

#define PIX(Q, RP01, RP23, RP45, RP67, SXF, RS, MUL, WS, A0, A1, A2, J) do { \
        half8_t d_ = (Q) - (MUL);                                        \
        half8_t dd_ = d_ * d_;                                           \
        float lw_ = fmaf((float)(((J) - 3) * ((J) - 3)), (SXF), (RS));   \
        lw_ = dot2acc(__builtin_shufflevector(dd_, dd_, 0, 1), RP01, lw_); \
        lw_ = dot2acc(__builtin_shufflevector(dd_, dd_, 2, 3), RP23, lw_); \
        lw_ = dot2acc(__builtin_shufflevector(dd_, dd_, 4, 5), RP45, lw_); \
        lw_ = dot2acc(__builtin_shufflevector(dd_, dd_, 6, 7), RP67, lw_); \
        float w_ = fast_exp2(lw_);                                       \
        if (!INTERIOR) w_ *= mrow_[(J)];                                 \
        WS += w_;                                                        \
        A0 = fmaf(w_, (float)(Q)[0], A0);                                \
        A1 = fmaf(w_, (float)(Q)[1], A1);                                \
        A2 = fmaf(w_, (float)(Q)[2], A2);                                \
    } while (0)

    // ---- row loop at unroll 2: scheduling region = 2 rows, so row i+1's
    // seven ds_read_b128 hoist over row i's ~500cy compute (live ~14 half8
    // = 56 VGPR + ~48 base ≈ 104 < 128 cap). unroll-1 (R6) exposed ~120cy
    // LDS latency per row; unroll-8 (R3-R5) demanded ~175 regs -> spill.
#pragma unroll 2
    for (int i = 0; i < 8; ++i) {
        const half8_t* lq_ = lp + i * SW;
        half8_t q0_ = lq_[0], q1_ = lq_[1], q2_ = lq_[2], q3_ = lq_[3],
                q4_ = lq_[4], q5_ = lq_[5], q6_ = lq_[6];
        const float* mrow_ = msk + (2 * ty + i) * SW + tx;
        (void)mrow_;
        if (i != 7) {  // contributes to pixel 0 (window rows 0..6)
            const float rs0_ = syf0 * (float)((i - 3) * (i - 3));
            PIX(q0_, rp01_0, rp23_0, rp45_0, rp67_0, sxf0, rs0_, fc0, ws0, a00, a01, a02, 0);
            PIX(q1_, rp01_0, rp23_0, rp45_0, rp67_0, sxf0, rs0_, fc0, ws0, a00, a01, a02, 1);
            PIX(q2_, rp01_0, rp23_0, rp45_0, rp67_0, sxf0, rs0_, fc0, ws0, a00, a01, a02, 2);
            PIX(q3_, rp01_0, rp23_0, rp45_0, rp67_0, sxf0, rs0_, fc0, ws0, a00, a01, a02, 3);
            PIX(q4_, rp01_0, rp23_0, rp45_0, rp67_0, sxf0, rs0_, fc0, ws0, a00, a01, a02, 4);
            PIX(q5_, rp01_0, rp23_0, rp45_0, rp67_0, sxf0, rs0_, fc0, ws0, a00, a01, a02, 5);
            PIX(q6_, rp01_0, rp23_0, rp45_0, rp67_0, sxf0, rs0_, fc0, ws0, a00, a01, a02, 6);
        }
        if (i != 0) {  // contributes to pixel 1 (its window rows 0..6 = halo 1..7)
            const float rs1_ = syf1 * (float)((i - 4) * (i - 4));
            PIX(q0_, rp01_1, rp23_1, rp45_1, rp67_1, sxf1, rs1_, fc1, ws1, a10, a11, a12, 0);
            PIX(q1_, rp01_1, rp23_1, rp45_1, rp67_1, sxf1, rs1_, fc1, ws1, a10, a11, a12, 1);
            PIX(q2_, rp01_1, rp23_1, rp45_1, rp67_1, sxf1, rs1_, fc1, ws1, a10, a11, a12, 2);
            PIX(q3_, rp01_1, rp23_1, rp45_1, rp67_1, sxf1, rs1_, fc1, ws1, a10, a11, a12, 3);
            PIX(q4_, rp01_1, rp23_1, rp45_1, rp67_1, sxf1, rs1_, fc1, ws1, a10, a11, a12, 4);
            PIX(q5_, rp01_1, rp23_1, rp45_1, rp67_1, sxf1, rs1_, fc1, ws1, a10, a11, a12, 5);
            PIX(q6_, rp01_1, rp23_1, rp45_1, rp67_1, sxf1, rs1_, fc1, ws1, a10, a11, a12, 6);
        }
    }
#undef PIX

    const float inv0 = 1.0f / ws0;
    const float inv1 = 1.0f / ws1;
    outb[pofs0]                 = a00 * inv0;
    outb[PLANE + pofs0]         = a01 * inv0;
    outb[2 * PLANE + pofs0]     = a02 * inv0;
    outb[pofs0 + W]             = a10 * inv1;
    outb[PLANE + pofs0 + W]     = a11 * inv1;
    outb[2 * PLANE + pofs0 + W] = a12 * inv1;
}

// VGPR-cap model (empirical): launch_bounds(256,N) caps at 256/N:
// (256,8)->32, (256,4)->64, (256,2)->128 (R4/R5). Scheduling-region model:
// window unroll-8 demands ~175 regs -> spills at any cap (R3-R5); unroll-1
// runs at 48 regs but exposes every LDS/global latency (R6 = 114us =
// baseline). unroll-2 is the engineered middle: ~104 regs, row i+1 loads
// overlap row i compute.
__global__ __launch_bounds__(TX * TY, 2) void bilateral_kernel(const float* __restrict__ in,
                                                               float* __restrict__ out)
{
    __shared__ __align__(16) half8_t tile[NPOS];
    __shared__ float msk[NPOS];
    const int b = blockIdx.z;
    const int gx0 = blockIdx.x * TX;
    const int gy0 = blockIdx.y * TILE_H;
    const float* inb = in + (size_t)b * CIN * PLANE;
    float* outb = out + (size_t)b * 3 * PLANE;

    const bool interior = (gx0 >= 3) && (gx0 + TX + 3 <= W) &&
                          (gy0 >= 3) && (gy0 + TILE_H + 3 <= H);
    if (interior)
        run_tile<true>(inb, outb, tile, msk, gy0, gx0);
    else
        run_tile<false>(inb, outb, tile, msk, gy0, gx0);
}

} // namespace

extern "C" void kernel_launch(void* const* d_in, const int* in_sizes, int n_in,
                              void* d_out, int out_size, void* d_ws, size_t ws_size,
                              hipStream_t stream)
{
    const float* in = (const float*)d_in[0];
    float* out = (float*)d_out;
    dim3 grid(W / TX, H / TILE_H, 2);
    dim3 block(TX, TY);
    hipLaunchKernelGGL(bilateral_kernel, grid, block, 0, stream, in, out);
}

// Round 8
// 254.777 us; speedup vs baseline: 1.6823x; 1.0029x over previous
//
#include <hip/hip_runtime.h>

namespace {

constexpr int H = 1024;
constexpr int W = 1024;
constexpr int PLANE = H * W;
constexpr int CIN = 18;     // total input channels
constexpr int C = 8;        // filterable channels
constexpr int TX = 16;
constexpr int TY = 16;      // threads in y; each thread does 2 vertical pixels
constexpr int TILE_H = 32;  // output rows per block
constexpr int SWD = 24;     // staged data width (16B-aligned float4 super-halo)
constexpr int PITCH = 25;   // LDS row pitch in records: 800B stride -> 2-way banks only
constexpr int SH = TILE_H + 6;  // 38 halo height
constexpr int NREC = SWD * SH;  // 912 meaningful records
constexpr int NCHUNK = 6 * SH;  // 228 float4-chunks (6 per row)
constexpr int GX = W / TX;      // 64
constexpr int GY = H / TILE_H;  // 32
constexpr int NWG = GX * GY * 2;        // 4096 (mult of 8 -> simple swizzle bijective)
constexpr float LOG2E = 1.44269504088896340736f;

typedef _Float16 half2_t __attribute__((ext_vector_type(2)));
typedef _Float16 half8_t __attribute__((ext_vector_type(8)));
typedef float float4_t __attribute__((ext_vector_type(4)));

__device__ __forceinline__ float dot2acc(half2_t a, half2_t b, float c) {
#if defined(__has_builtin)
#if __has_builtin(__builtin_amdgcn_fdot2)
    return __builtin_amdgcn_fdot2(a, b, c, false);
#else
    return fmaf((float)a[0], (float)b[0], fmaf((float)a[1], (float)b[1], c));
#endif
#else
    return fmaf((float)a[0], (float)b[0], fmaf((float)a[1], (float)b[1], c));
#endif
}

__device__ __forceinline__ float fast_exp2(float x) {
#if defined(__has_builtin)
#if __has_builtin(__builtin_amdgcn_exp2f)
    return __builtin_amdgcn_exp2f(x);
#else
    return exp2f(x);
#endif
#else
    return exp2f(x);
#endif
}

template<bool INTERIOR>
__device__ __forceinline__ void run_tile(const float* __restrict__ inb,
                                         float* __restrict__ outb,
                                         half8_t* __restrict__ tile,
                                         float* __restrict__ msk,
                                         int gy0, int gx0)
{
    const int tx = threadIdx.x, ty = threadIdx.y;
    const int tid = ty * TX + tx;

    const int o0 = gy0 + 2 * ty;      // first output row of this thread
    const int gx = gx0 + tx;
    const int pofs0 = o0 * W + gx;    // pixel 0; pixel 1 = pofs0 + W

    // ---- per-pixel params for BOTH pixels first (their global latency
    // overlaps the staging loads + barrier). Packed pairwise.
    half2_t rp01_0, rp23_0, rp45_0, rp67_0;
    half2_t rp01_1, rp23_1, rp45_1, rp67_1;
    float sxf0, syf0, sxf1, syf1;
    {
        const float* pp = inb + (size_t)C * PLANE + pofs0;
#define PAIR(DST0, DST1, CA, CB) do {                                     \
        float a0_ = pp[(size_t)(CA) * PLANE];                             \
        float b0_ = pp[(size_t)(CB) * PLANE];                             \
        float a1_ = pp[(size_t)(CA) * PLANE + W];                         \
        float b1_ = pp[(size_t)(CB) * PLANE + W];                         \
        DST0 = half2_t{(_Float16)(-(a0_ * a0_) * LOG2E),                  \
                       (_Float16)(-(b0_ * b0_) * LOG2E)};                 \
        DST1 = half2_t{(_Float16)(-(a1_ * a1_) * LOG2E),                  \
                       (_Float16)(-(b1_ * b1_) * LOG2E)};                 \
    } while (0)
        PAIR(rp01_0, rp01_1, 0, 1);
        PAIR(rp23_0, rp23_1, 2, 3);
        PAIR(rp45_0, rp45_1, 4, 5);
        PAIR(rp67_0, rp67_1, 6, 7);
#undef PAIR
        float px0 = pp[(size_t)8 * PLANE];
        float py0 = pp[(size_t)9 * PLANE];
        float px1 = pp[(size_t)8 * PLANE + W];
        float py1 = pp[(size_t)9 * PLANE + W];
        sxf0 = -(px0 * px0) * LOG2E;  syf0 = -(py0 * py0) * LOG2E;
        sxf1 = -(px1 * px1) * LOG2E;  syf1 = -(py1 * py1) * LOG2E;
    }

    if (INTERIOR) {
        // ---- float4 staging: one thread per (halo row, 4-px chunk).
        // 8 aligned float4 loads (1KB/wave-instr) -> 4 packed half8 recs.
        // This replaces ~26 scalar dword loads/thread (R0-R7's 2.25TB/s
        // effective-BW ceiling came from that scalar 88B-segment pattern).
        if (tid < NCHUNK) {
            int y = tid / 6;
            int xc = tid - y * 6;
            const float* p = inb + (size_t)(gy0 - 3 + y) * W + (gx0 - 4 + xc * 4);
            float4_t v0 = *reinterpret_cast<const float4_t*>(p);
            float4_t v1 = *reinterpret_cast<const float4_t*>(p + (size_t)1 * PLANE);
            float4_t v2 = *reinterpret_cast<const float4_t*>(p + (size_t)2 * PLANE);
            float4_t v3 = *reinterpret_cast<const float4_t*>(p + (size_t)3 * PLANE);
            float4_t v4 = *reinterpret_cast<const float4_t*>(p + (size_t)4 * PLANE);
            float4_t v5 = *reinterpret_cast<const float4_t*>(p + (size_t)5 * PLANE);
            float4_t v6 = *reinterpret_cast<const float4_t*>(p + (size_t)6 * PLANE);
            float4_t v7 = *reinterpret_cast<const float4_t*>(p + (size_t)7 * PLANE);
            const int tb = y * PITCH + xc * 4;
#define PACK(K) do { half8_t h_;                                          \
            h_[0] = (_Float16)v0[K]; h_[1] = (_Float16)v1[K];             \
            h_[2] = (_Float16)v2[K]; h_[3] = (_Float16)v3[K];             \
            h_[4] = (_Float16)v4[K]; h_[5] = (_Float16)v5[K];             \
            h_[6] = (_Float16)v6[K]; h_[7] = (_Float16)v7[K];             \
            tile[tb + (K)] = h_; } while (0)
            PACK(0); PACK(1); PACK(2); PACK(3);
#undef PACK
        }
    } else {
        // ---- boundary fallback: scalar per-record with bounds check
#pragma unroll 1
        for (int idx = tid; idx < NREC; idx += TX * TY) {
            int y = idx / SWD;
            int x = idx - y * SWD;
            int sy_ = gy0 + y - 3;
            int sx_ = gx0 + x - 4;
            half8_t hv;
            const int sofs = y * PITCH + x;
            if ((unsigned)sy_ < (unsigned)H && (unsigned)sx_ < (unsigned)W) {
                const float* p = inb + sy_ * W + sx_;
#pragma unroll
                for (int c = 0; c < C; ++c) hv[c] = (_Float16)p[(size_t)c * PLANE];
                msk[sofs] = 1.0f;
            } else {
#pragma unroll
                for (int c = 0; c < C; ++c) hv[c] = (_Float16)0.0f;
                msk[sofs] = 0.0f;
            }
            tile[sofs] = hv;
        }
    }
    __syncthreads();

    // window origin: data x = 1 + tx (super-halo starts at gx0-4, window at gx0-3)
    const half8_t* lp = tile + (2 * ty) * PITCH + (tx + 1);
    const half8_t fc0 = lp[3 * PITCH + 3];  // center of px0
    const half8_t fc1 = lp[4 * PITCH + 3];  // center of px1

    float a00 = 0.f, a01 = 0.f, a02 = 0.f, ws0 = 0.f;
    float a10 = 0.f, a11 = 0.f, a12 = 0.f, ws1 = 0.f;

#define PIX(Q, RP01, RP23, RP45, RP67, SXF, RS, MUL, WS, A0, A1, A2, J) do { \
        half8_t d_ = (Q) - (MUL);                                        \
        half8_t dd_ = d_ * d_;                                           \
        float lw_ = fmaf((float)(((J) - 3) * ((J) - 3)), (SXF), (RS));   \
        lw_ = dot2acc(__builtin_shufflevector(dd_, dd_, 0, 1), RP01, lw_); \
        lw_ = dot2acc(__builtin_shufflevector(dd_, dd_, 2, 3), RP23, lw_); \
        lw_ = dot2acc(__builtin_shufflevector(dd_, dd_, 4, 5), RP45, lw_); \
        lw_ = dot2acc(__builtin_shufflevector(dd_, dd_, 6, 7), RP67, lw_); \
        float w_ = fast_exp2(lw_);                                       \
        if (!INTERIOR) w_ *= mrow_[(J)];                                 \
        WS += w_;                                                        \
        A0 = fmaf(w_, (float)(Q)[0], A0);                                \
        A1 = fmaf(w_, (float)(Q)[1], A1);                                \
        A2 = fmaf(w_, (float)(Q)[2], A2);                                \
    } while (0)

    // ---- row loop as a real loop (R6: bounds scheduler region, 48 VGPR,
    // no spill; full unroll demanded ~175 regs -> GB-scale spill R3-R5)
#pragma unroll 1
    for (int i = 0; i < 8; ++i) {
        const half8_t* lq_ = lp + i * PITCH;
        half8_t q0_ = lq_[0], q1_ = lq_[1], q2_ = lq_[2], q3_ = lq_[3],
                q4_ = lq_[4], q5_ = lq_[5], q6_ = lq_[6];
        const float* mrow_ = msk + (2 * ty + i) * PITCH + (tx + 1);
        (void)mrow_;
        if (i != 7) {  // contributes to pixel 0 (window rows 0..6)
            const float rs0_ = syf0 * (float)((i - 3) * (i - 3));
            PIX(q0_, rp01_0, rp23_0, rp45_0, rp67_0, sxf0, rs0_, fc0, ws0, a00, a01, a02, 0);
            PIX(q1_, rp01_0, rp23_0, rp45_0, rp67_0, sxf0, rs0_, fc0, ws0, a00, a01, a02, 1);
            PIX(q2_, rp01_0, rp23_0, rp45_0, rp67_0, sxf0, rs0_, fc0, ws0, a00, a01, a02, 2);
            PIX(q3_, rp01_0, rp23_0, rp45_0, rp67_0, sxf0, rs0_, fc0, ws0, a00, a01, a02, 3);
            PIX(q4_, rp01_0, rp23_0, rp45_0, rp67_0, sxf0, rs0_, fc0, ws0, a00, a01, a02, 4);
            PIX(q5_, rp01_0, rp23_0, rp45_0, rp67_0, sxf0, rs0_, fc0, ws0, a00, a01, a02, 5);
            PIX(q6_, rp01_0, rp23_0, rp45_0, rp67_0, sxf0, rs0_, fc0, ws0, a00, a01, a02, 6);
        }
        if (i != 0) {  // contributes to pixel 1 (its window rows = halo 1..7)
            const float rs1_ = syf1 * (float)((i - 4) * (i - 4));
            PIX(q0_, rp01_1, rp23_1, rp45_1, rp67_1, sxf1, rs1_, fc1, ws1, a10, a11, a12, 0);
            PIX(q1_, rp01_1, rp23_1, rp45_1, rp67_1, sxf1, rs1_, fc1, ws1, a10, a11, a12, 1);
            PIX(q2_, rp01_1, rp23_1, rp45_1, rp67_1, sxf1, rs1_, fc1, ws1, a10, a11, a12, 2);
            PIX(q3_, rp01_1, rp23_1, rp45_1, rp67_1, sxf1, rs1_, fc1, ws1, a10, a11, a12, 3);
            PIX(q4_, rp01_1, rp23_1, rp45_1, rp67_1, sxf1, rs1_, fc1, ws1, a10, a11, a12, 4);
            PIX(q5_, rp01_1, rp23_1, rp45_1, rp67_1, sxf1, rs1_, fc1, ws1, a10, a11, a12, 5);
            PIX(q6_, rp01_1, rp23_1, rp45_1, rp67_1, sxf1, rs1_, fc1, ws1, a10, a11, a12, 6);
        }
    }
#undef PIX

    const float inv0 = 1.0f / ws0;
    const float inv1 = 1.0f / ws1;
    outb[pofs0]                 = a00 * inv0;
    outb[PLANE + pofs0]         = a01 * inv0;
    outb[2 * PLANE + pofs0]     = a02 * inv0;
    outb[pofs0 + W]             = a10 * inv1;
    outb[PLANE + pofs0 + W]     = a11 * inv1;
    outb[2 * PLANE + pofs0 + W] = a12 * inv1;
}

// R0-R7 lesson: every spill-free variant ran at dur = hbm_bytes/2.25TB/s ->
// HBM-pattern-bound, not latency/VALU. R8: float4 staging (3.3x fewer,
// 4x bigger VMEM) + XCD-chunked block swizzle (halo re-reads hit same-XCD
// L2) + pitch-25 LDS (2-way banks). VGPR-cap: launch_bounds(256,N) caps
// at 256/N; keep (256,2)=128.
__global__ __launch_bounds__(TX * TY, 2) void bilateral_kernel(const float* __restrict__ in,
                                                               float* __restrict__ out)
{
    __shared__ __align__(16) half8_t tile[PITCH * SH];
    __shared__ float msk[PITCH * SH];

    // XCD-chunked swizzle (T1): hardware round-robins bid%8 across XCDs;
    // give XCD k the contiguous tile band [k*512, (k+1)*512) so adjacent
    // tiles (sharing halo lines) land in the same XCD's L2. Bijective
    // since NWG=4096 is a multiple of 8.
    const int bid = blockIdx.x;
    const int fin = (bid & 7) * (NWG / 8) + (bid >> 3);
    const int bx = fin & (GX - 1);
    const int by = (fin >> 6) & (GY - 1);
    const int bz = fin >> 11;

    const int gx0 = bx * TX;
    const int gy0 = by * TILE_H;
    const float* inb = in + (size_t)bz * CIN * PLANE;
    float* outb = out + (size_t)bz * 3 * PLANE;

    const bool interior = (gx0 >= 4) && (gx0 + TX + 4 <= W) &&
                          (gy0 >= 3) && (gy0 + TILE_H + 3 <= H);
    if (interior)
        run_tile<true>(inb, outb, tile, msk, gy0, gx0);
    else
        run_tile<false>(inb, outb, tile, msk, gy0, gx0);
}

} // namespace

extern "C" void kernel_launch(void* const* d_in, const int* in_sizes, int n_in,
                              void* d_out, int out_size, void* d_ws, size_t ws_size,
                              hipStream_t stream)
{
    const float* in = (const float*)d_in[0];
    float* out = (float*)d_out;
    dim3 grid(NWG, 1, 1);
    dim3 block(TX, TY);
    hipLaunchKernelGGL(bilateral_kernel, grid, block, 0, stream, in, out);
}